// Round 1
// baseline (345.522 us; speedup 1.0000x reference)
//
#include <hip/hip_runtime.h>
#include <hip/hip_bf16.h>
#include <hip/hip_cooperative_groups.h>

namespace cg = cooperative_groups;

// Problem constants
#define CIN   128
#define COUT  64
#define HW    16384   // 128*128

typedef __hip_bfloat16 bf16;

// ---- fused-kernel workspace layout (float offsets), total ~4.4 MB ----
#define F_PS    0u          // bf16[512 blk][64 k][64 o] partial bin sums (1048576 f-equiv)
#define F_PC    1048576u    // f32 [2][64][256] partial bin counts
#define F_MEANS 1081344u    // f32 [2][64][64]
#define F_INV   1089536u    // f32 [64][64]
#define F_ADJM  1093632u    // f32 [2][64][64]
#define F_BNACC 1101824u    // f32 [32 replicas][128] BN accumulators (zeroed in B1)

// ---- legacy offsets (fallback path only) ----
#define OFF_XT    0u
#define OFF_PS    1048576u
#define OFF_PC    2097152u
#define OFF_MEANS 2129920u
#define OFF_DIAG  2138112u
#define OFF_INV   2138240u
#define OFF_ADJM  2142336u
#define OFF_BNP   2150528u

__device__ __forceinline__ unsigned short f2bfu(float f) {
  union { bf16 h; unsigned short u; } cv; cv.h = __float2bfloat16(f); return cv.u;
}
__device__ __forceinline__ float bf2f(unsigned short u) {
  union { unsigned int i; float f; } cv; cv.i = ((unsigned int)u) << 16; return cv.f;
}

#define FMA16() do { \
  acc[ 0]=fmaf(xv.x,wv.x,acc[ 0]); acc[ 1]=fmaf(xv.y,wv.x,acc[ 1]); \
  acc[ 2]=fmaf(xv.z,wv.x,acc[ 2]); acc[ 3]=fmaf(xv.w,wv.x,acc[ 3]); \
  acc[ 4]=fmaf(xv.x,wv.y,acc[ 4]); acc[ 5]=fmaf(xv.y,wv.y,acc[ 5]); \
  acc[ 6]=fmaf(xv.z,wv.y,acc[ 6]); acc[ 7]=fmaf(xv.w,wv.y,acc[ 7]); \
  acc[ 8]=fmaf(xv.x,wv.z,acc[ 8]); acc[ 9]=fmaf(xv.y,wv.z,acc[ 9]); \
  acc[10]=fmaf(xv.z,wv.z,acc[10]); acc[11]=fmaf(xv.w,wv.z,acc[11]); \
  acc[12]=fmaf(xv.x,wv.w,acc[12]); acc[13]=fmaf(xv.y,wv.w,acc[13]); \
  acc[14]=fmaf(xv.z,wv.w,acc[14]); acc[15]=fmaf(xv.w,wv.w,acc[15]); \
} while (0)

// ============================================================================
// FUSED cooperative kernel: 512 blocks x 256 thr, 48 KB LDS (3 blk/CU capacity
// -> 512-block co-residency safe). Each thread owns a 4px x 4o xt tile in
// registers for the whole kernel; xt never goes to HBM.
// Phases: A einsum+bins | B1 means+inv+zero | B2 adj+adjm | C BN partials | D out
// ============================================================================
__global__ __launch_bounds__(256, 2) void fused_gnn(
    const float* __restrict__ x, const int* __restrict__ index,
    const float* __restrict__ Wft, const float* __restrict__ Wm,
    const float* __restrict__ gamma, const float* __restrict__ beta,
    float* __restrict__ ws, float* __restrict__ out)
{
  __shared__ __align__(16) float smem[12288];   // 48 KB
  cg::grid_group grid = cg::this_grid();
  const int blk = blockIdx.x, tid = threadIdx.x;
  const int b = blk >> 8, ps = blk & 255;
  const int px_grp = tid & 15, o_grp = tid >> 4;
  const int px = ps * 64 + px_grp * 4, o0 = o_grp * 4;

  // ===================== Phase A: einsum slab + bin partials =====================
  float acc[16];
#pragma unroll
  for (int j = 0; j < 16; ++j) acc[j] = 0.f;
  {
    float* xl = smem;          // [128 c][64 px]  (32 KB)
    float* wl = smem + 8192;   // [64 c][64 o]    (16 KB, Wft staged in 2 halves)
    const float* xg = x + (size_t)b * CIN * HW + ps * 64;
#pragma unroll
    for (int j = 0; j < 8; ++j) {
      const int fj = j * 256 + tid;
      const int c = fj >> 4, q4 = (fj & 15) * 4;
      *(float4*)&xl[c * 64 + q4] = *(const float4*)(xg + (size_t)c * HW + q4);
    }
#pragma unroll
    for (int j = 0; j < 4; ++j) {
      const int fj = j * 256 + tid;
      const int c = fj >> 4, q4 = (fj & 15) * 4;
      *(float4*)&wl[c * 64 + q4] = *(const float4*)(Wft + c * 64 + q4);
    }
    __syncthreads();
#pragma unroll 8
    for (int c = 0; c < 64; ++c) {
      const float4 xv = *(const float4*)&xl[c * 64 + px_grp * 4];
      const float4 wv = *(const float4*)&wl[c * 64 + o0];
      FMA16();
    }
    __syncthreads();           // wl half-0 reads done
#pragma unroll
    for (int j = 0; j < 4; ++j) {
      const int fj = j * 256 + tid;
      const int c = fj >> 4, q4 = (fj & 15) * 4;
      *(float4*)&wl[c * 64 + q4] = *(const float4*)(Wft + (64 + c) * 64 + q4);
    }
    __syncthreads();
#pragma unroll 8
    for (int c = 0; c < 64; ++c) {
      const float4 xv = *(const float4*)&xl[(64 + c) * 64 + px_grp * 4];
      const float4 wv = *(const float4*)&wl[c * 64 + o0];
      FMA16();
    }
  }
  const int4 kv = *(const int4*)(index + b * HW + px);
  const int kk[4] = {kv.x, kv.y, kv.z, kv.w};   // kept in regs for phase C
  __syncthreads();                               // all LDS compute reads done
  {
    float* bins = smem;                          // [64 k][68] padded
    float* cnt  = smem + 64 * 68;                // [64]
    for (int i = tid; i < 64 * 68 + 64; i += 256) smem[i] = 0.f;
    __syncthreads();
#pragma unroll
    for (int pj = 0; pj < 4; ++pj) {
      const int kb = kk[pj] * 68 + o0;
      atomicAdd(&bins[kb    ], acc[ 0 + pj]);
      atomicAdd(&bins[kb + 1], acc[ 4 + pj]);
      atomicAdd(&bins[kb + 2], acc[ 8 + pj]);
      atomicAdd(&bins[kb + 3], acc[12 + pj]);
    }
    if (o_grp == 0) {   // exactly one thread per px
#pragma unroll
      for (int pj = 0; pj < 4; ++pj) atomicAdd(&cnt[kk[pj]], 1.f);
    }
    __syncthreads();
    unsigned short* pb = (unsigned short*)(ws + F_PS) + (size_t)blk * 4096;
    {
      const int k = tid >> 2, ob = (tid & 3) * 16;
#pragma unroll
      for (int q = 0; q < 4; ++q) {
        const float4 v = *(const float4*)&bins[k * 68 + ob + q * 4];
        ushort4 u;
        u.x = f2bfu(v.x); u.y = f2bfu(v.y); u.z = f2bfu(v.z); u.w = f2bfu(v.w);
        *(ushort4*)(pb + k * 64 + ob + q * 4) = u;
      }
    }
    if (tid < 64) ws[F_PC + (size_t)(b * 64 + tid) * 256 + ps] = cnt[tid];
  }
  grid.sync();   // ======================= sync 1 =======================

  // ===== Phase B1: means (blk 0..127) | zero BNACC (blk 128) | inverse (blk 511)
  if (blk < 128) {
    const int bb = blk >> 6, k = blk & 63;
    float* red   = smem;           // [16][64]
    float* lds_c = smem + 1024;    // [4]
    const unsigned short* psu = (const unsigned short*)(ws + F_PS);
    const int o4 = (tid & 15) * 4, chunk = tid >> 4;
    float s4[4] = {0.f, 0.f, 0.f, 0.f};
#pragma unroll 4
    for (int i = 0; i < 16; ++i) {
      const int slab = chunk * 16 + i;
      const ushort4 u = *(const ushort4*)(psu + (size_t)(bb * 256 + slab) * 4096 + k * 64 + o4);
      s4[0] += bf2f(u.x); s4[1] += bf2f(u.y); s4[2] += bf2f(u.z); s4[3] += bf2f(u.w);
    }
#pragma unroll
    for (int j = 0; j < 4; ++j) red[chunk * 64 + o4 + j] = s4[j];
    float cv = ws[F_PC + (size_t)(bb * 64 + k) * 256 + tid];
#pragma unroll
    for (int m = 32; m; m >>= 1) cv += __shfl_xor(cv, m, 64);
    if ((tid & 63) == 0) lds_c[tid >> 6] = cv;
    __syncthreads();
    if (tid < 64) {
      float m_raw = 0.f;
#pragma unroll
      for (int ch = 0; ch < 16; ++ch) m_raw += red[ch * 64 + tid];
      const float cntv = lds_c[0] + lds_c[1] + lds_c[2] + lds_c[3];
      const float denom = cntv + ((cntv == 0.f) ? 1.f : 0.f);
      ws[F_MEANS + (size_t)(bb * 64 + k) * 64 + tid] = m_raw / denom;
    }
  } else if (blk == 128) {
    for (int e = tid; e < 4096; e += 256) ws[F_BNACC + e] = 0.f;
  } else if (blk == 511) {
    // inv(Wm Wm^T) — blocked Gauss-Jordan, 16 panels of 4 pivots (proven R7 form)
    float* wm = smem;            // [64][68]
    float* Rb = smem + 4608;     // [2][4][64]
    float* Cb = smem + 5120;     // [2][64][4]
    for (int e = tid; e < 4096; e += 256) wm[(e >> 6) * 68 + (e & 63)] = Wm[e];
    __syncthreads();
    const int ig = tid >> 4, jg = tid & 15;
    const int i0 = ig << 2, j0 = jg << 2;
    float c4[16];
#pragma unroll
    for (int q = 0; q < 16; ++q) c4[q] = 0.f;
    for (int cq = 0; cq < 64; cq += 4) {
      float4 a[4], bb2[4];
#pragma unroll
      for (int ii = 0; ii < 4; ++ii) a[ii]   = *(const float4*)&wm[(i0 + ii) * 68 + cq];
#pragma unroll
      for (int jj = 0; jj < 4; ++jj) bb2[jj] = *(const float4*)&wm[(j0 + jj) * 68 + cq];
#pragma unroll
      for (int ii = 0; ii < 4; ++ii)
#pragma unroll
        for (int jj = 0; jj < 4; ++jj)
          c4[ii*4+jj] = fmaf(a[ii].x, bb2[jj].x, fmaf(a[ii].y, bb2[jj].y,
                        fmaf(a[ii].z, bb2[jj].z, fmaf(a[ii].w, bb2[jj].w, c4[ii*4+jj]))));
    }
    __syncthreads();
    __builtin_amdgcn_s_setprio(3);
    int buf = 0;
#pragma unroll 1   // MUST stay rolled (I$ thrash)
    for (int p = 0; p < 16; ++p) {
      const int P = p << 2;
      float* Rp = Rb + buf * 256;
      float* Cp = Cb + buf * 256;
      if (ig == p) {
#pragma unroll
        for (int r = 0; r < 4; ++r) {
          float4 t; t.x = c4[r*4+0]; t.y = c4[r*4+1]; t.z = c4[r*4+2]; t.w = c4[r*4+3];
          *(float4*)&Rp[r * 64 + j0] = t;
        }
      }
      if (jg == p) {
#pragma unroll
        for (int ii = 0; ii < 4; ++ii) {
          float4 t; t.x = c4[ii*4+0]; t.y = c4[ii*4+1]; t.z = c4[ii*4+2]; t.w = c4[ii*4+3];
          *(float4*)&Cp[(i0 + ii) * 4] = t;
        }
      }
      __syncthreads();
      float dd[16], cc[16], rr[16];
#pragma unroll
      for (int r = 0; r < 4; ++r) *(float4*)&dd[r * 4] = *(const float4*)&Rp[r * 64 + P];
#pragma unroll
      for (int ii = 0; ii < 4; ++ii) *(float4*)&cc[ii * 4] = *(const float4*)&Cp[(i0 + ii) * 4];
#pragma unroll
      for (int r = 0; r < 4; ++r) *(float4*)&rr[r * 4] = *(const float4*)&Rp[r * 64 + j0];
#pragma unroll
      for (int k2 = 0; k2 < 4; ++k2) {
        const float rp = __builtin_amdgcn_rcpf(dd[k2 * 4 + k2]);
        float ai[4], s[4];
#pragma unroll
        for (int j = 0; j < 4; ++j) s[j] = dd[k2 * 4 + j];
#pragma unroll
        for (int i = 0; i < 4; ++i) ai[i] = (i == k2) ? (rp - 1.0f) : (-dd[i * 4 + k2] * rp);
#pragma unroll
        for (int i = 0; i < 4; ++i)
#pragma unroll
          for (int j = 0; j < 4; ++j) dd[i * 4 + j] = fmaf(ai[i], s[j], dd[i * 4 + j]);
#pragma unroll
        for (int i = 0; i < 4; ++i) dd[i * 4 + k2] = (i == k2) ? rp : ai[i];
      }
      float T[16];
#pragma unroll
      for (int ii = 0; ii < 4; ++ii)
#pragma unroll
        for (int c = 0; c < 4; ++c) {
          float t = cc[ii*4+0] * dd[0*4+c];
          t = fmaf(cc[ii*4+1], dd[1*4+c], t);
          t = fmaf(cc[ii*4+2], dd[2*4+c], t);
          t = fmaf(cc[ii*4+3], dd[3*4+c], t);
          T[ii*4+c] = t;
        }
      if (ig == p && jg == p) {
#pragma unroll
        for (int q = 0; q < 16; ++q) c4[q] = dd[q];
      } else if (ig == p) {
#pragma unroll
        for (int r = 0; r < 4; ++r)
#pragma unroll
          for (int jj = 0; jj < 4; ++jj) {
            float t = dd[r*4+0] * rr[0*4+jj];
            t = fmaf(dd[r*4+1], rr[1*4+jj], t);
            t = fmaf(dd[r*4+2], rr[2*4+jj], t);
            t = fmaf(dd[r*4+3], rr[3*4+jj], t);
            c4[r*4+jj] = t;
          }
      } else if (jg == p) {
#pragma unroll
        for (int q = 0; q < 16; ++q) c4[q] = -T[q];
      } else {
#pragma unroll
        for (int ii = 0; ii < 4; ++ii)
#pragma unroll
          for (int jj = 0; jj < 4; ++jj) {
            float t = c4[ii*4+jj];
            t = fmaf(-T[ii*4+0], rr[0*4+jj], t);
            t = fmaf(-T[ii*4+1], rr[1*4+jj], t);
            t = fmaf(-T[ii*4+2], rr[2*4+jj], t);
            t = fmaf(-T[ii*4+3], rr[3*4+jj], t);
            c4[ii*4+jj] = t;
          }
      }
      buf ^= 1;
    }
    __builtin_amdgcn_s_setprio(0);
#pragma unroll
    for (int ii = 0; ii < 4; ++ii)
#pragma unroll
      for (int jj = 0; jj < 4; ++jj)
        ws[F_INV + (size_t)(i0 + ii) * 64 + j0 + jj] = c4[ii*4+jj];
  }
  grid.sync();   // ======================= sync 2 =======================

  // ===== Phase B2 (blk 0..15): full T + diag redundantly, 8 adj rows + adjm =====
  if (blk < 16) {
    const int bb = blk >> 3, r0 = (blk & 7) << 3;
    float* means_s = smem;            // [64][68]
    float* inv_s   = smem + 4352;     // [64][68]
    float* T_s     = smem + 8704;     // [8][68]
    float* adj_s   = smem + 9248;     // [8][68]
    float* d_s     = smem + 9792;     // [64]
    const float* mg = ws + F_MEANS + (size_t)bb * 4096;
    for (int e = tid; e < 4096; e += 256) means_s[(e >> 6) * 68 + (e & 63)] = mg[e];
    for (int e = tid; e < 4096; e += 256) inv_s[(e >> 6) * 68 + (e & 63)] = ws[F_INV + e];
    __syncthreads();
    {   // thread = (row j, 16-col strip): T[j][oq..oq+15], d_j partial
      const int j = tid >> 2, oq = (tid & 3) << 4;
      float4 Ta[4];
#pragma unroll
      for (int v = 0; v < 4; ++v) { Ta[v].x = 0.f; Ta[v].y = 0.f; Ta[v].z = 0.f; Ta[v].w = 0.f; }
      for (int c = 0; c < 64; ++c) {
        const float mv = means_s[j * 68 + c];
#pragma unroll
        for (int v = 0; v < 4; ++v) {
          const float4 iv = *(const float4*)&inv_s[c * 68 + oq + v * 4];
          Ta[v].x = fmaf(mv, iv.x, Ta[v].x); Ta[v].y = fmaf(mv, iv.y, Ta[v].y);
          Ta[v].z = fmaf(mv, iv.z, Ta[v].z); Ta[v].w = fmaf(mv, iv.w, Ta[v].w);
        }
      }
      float dp = 0.f;
#pragma unroll
      for (int v = 0; v < 4; ++v) {
        const float4 mvv = *(const float4*)&means_s[j * 68 + oq + v * 4];
        dp = fmaf(Ta[v].x, mvv.x, dp); dp = fmaf(Ta[v].y, mvv.y, dp);
        dp = fmaf(Ta[v].z, mvv.z, dp); dp = fmaf(Ta[v].w, mvv.w, dp);
      }
      dp += __shfl_xor(dp, 1, 64);
      dp += __shfl_xor(dp, 2, 64);
      if ((tid & 3) == 0) d_s[j] = dp;
      if (j >= r0 && j < r0 + 8) {
#pragma unroll
        for (int v = 0; v < 4; ++v) *(float4*)&T_s[(j - r0) * 68 + oq + v * 4] = Ta[v];
      }
    }
    __syncthreads();
    {   // q_ij = d_i + d_j - 2 T_i·m_j ; adj = exp(-sqrt(max(q,1e-12)))
      const int i = tid >> 5, jb = tid & 31;
#pragma unroll
      for (int jj = 0; jj < 2; ++jj) {
        const int jc = jb + (jj << 5);
        float4 p4 = {0.f, 0.f, 0.f, 0.f};
        for (int dq = 0; dq < 64; dq += 4) {
          const float4 tv = *(const float4*)&T_s[i * 68 + dq];
          const float4 mv = *(const float4*)&means_s[jc * 68 + dq];
          p4.x = fmaf(tv.x, mv.x, p4.x); p4.y = fmaf(tv.y, mv.y, p4.y);
          p4.z = fmaf(tv.z, mv.z, p4.z); p4.w = fmaf(tv.w, mv.w, p4.w);
        }
        const float p = (p4.x + p4.y) + (p4.z + p4.w);
        const float q = d_s[r0 + i] + d_s[jc] - 2.f * p;
        adj_s[i * 68 + jc] = __expf(-sqrtf(fmaxf(q, 1e-12f)));
      }
    }
    __syncthreads();
    if (tid < 128) {   // adjm rows
      const int i = tid >> 4, oq4 = (tid & 15) << 2;
      float4 am = {0.f, 0.f, 0.f, 0.f};
      for (int jc = 0; jc < 64; ++jc) {
        const float av = adj_s[i * 68 + jc];
        const float4 mv = *(const float4*)&means_s[jc * 68 + oq4];
        am.x = fmaf(av, mv.x, am.x); am.y = fmaf(av, mv.y, am.y);
        am.z = fmaf(av, mv.z, am.z); am.w = fmaf(av, mv.w, am.w);
      }
      *(float4*)(ws + F_ADJM + (size_t)(bb * 64 + r0 + i) * 64 + oq4) = am;
    }
  }
  grid.sync();   // ======================= sync 3 =======================

  // ===== Phase C: f = relu(acc + adjm[k]) in regs; BN partials -> 32 replicas =====
  {
    float* adjm_s = smem;          // [64 k][67] (odd stride: (67k+o)%32 spreads banks)
    float* accum  = smem + 4288;   // [128] {sum[64], ssq[64]}
    const float* ag = ws + F_ADJM + (size_t)b * 4096;
    for (int e = tid; e < 4096; e += 256) adjm_s[(e >> 6) * 67 + (e & 63)] = ag[e];
    if (tid < 128) accum[tid] = 0.f;
    __syncthreads();
    float s[4] = {0.f, 0.f, 0.f, 0.f}, q[4] = {0.f, 0.f, 0.f, 0.f};
#pragma unroll
    for (int pj = 0; pj < 4; ++pj) {
      const int kb = kk[pj] * 67 + o0;
#pragma unroll
      for (int oj = 0; oj < 4; ++oj) {
        const float f = fmaxf(acc[oj * 4 + pj] + adjm_s[kb + oj], 0.f);
        acc[oj * 4 + pj] = f;             // overwrite: acc now holds f for phase D
        s[oj] += f; q[oj] = fmaf(f, f, q[oj]);
      }
    }
#pragma unroll
    for (int m = 1; m < 16; m <<= 1) {    // reduce over the 16 px_grp lanes
#pragma unroll
      for (int oj = 0; oj < 4; ++oj) {
        s[oj] += __shfl_xor(s[oj], m, 64);
        q[oj] += __shfl_xor(q[oj], m, 64);
      }
    }
    if ((tid & 15) == 0) {                // one lane per o_grp -> 128 distinct addrs
#pragma unroll
      for (int oj = 0; oj < 4; ++oj) {
        atomicAdd(&accum[o0 + oj], s[oj]);
        atomicAdd(&accum[64 + o0 + oj], q[oj]);
      }
    }
    __syncthreads();
    if (tid < 128)   // 16 blocks per replica -> low contention
      atomicAdd(ws + F_BNACC + (size_t)(blk & 31) * 128 + tid, accum[tid]);
  }
  grid.sync();   // ======================= sync 4 =======================

  // ===== Phase D: redundant 32-replica reduce, then out = f*sc + sh =====
  {
    float* sc_s = smem;        // [64]
    float* sh_s = smem + 64;   // [64]
    if (tid < 64) {
      float s = 0.f, qq = 0.f;
#pragma unroll
      for (int r = 0; r < 32; ++r) {
        s  += ws[F_BNACC + r * 128 + tid];
        qq += ws[F_BNACC + r * 128 + 64 + tid];
      }
      const float mean = s * (1.f / 32768.f);
      const float var  = qq * (1.f / 32768.f) - mean * mean;
      const float sc = gamma[tid] * rsqrtf(var + 1e-5f);
      sc_s[tid] = sc;
      sh_s[tid] = fmaf(-mean, sc, beta[tid]);
    }
    __syncthreads();
#pragma unroll
    for (int oj = 0; oj < 4; ++oj) {
      const float c_ = sc_s[o0 + oj], h_ = sh_s[o0 + oj];
      float4 o4;
      o4.x = fmaf(acc[oj * 4 + 0], c_, h_);
      o4.y = fmaf(acc[oj * 4 + 1], c_, h_);
      o4.z = fmaf(acc[oj * 4 + 2], c_, h_);
      o4.w = fmaf(acc[oj * 4 + 3], c_, h_);
      *(float4*)(out + (size_t)(b * 64 + o0 + oj) * HW + px) = o4;
    }
  }
}

// ============================================================================
// Legacy 5-kernel pipeline (fallback if cooperative launch is unavailable).
// Verbatim from the 121 µs baseline.
// ============================================================================
__global__ __launch_bounds__(256, 2) void k1_xt_bins_inv(
    const float* __restrict__ x, const int* __restrict__ index,
    const float* __restrict__ Wft, const float* __restrict__ Wm,
    float* __restrict__ ws)
{
  __shared__ __align__(16) float smem[16384];
  const int blk = blockIdx.x, tid = threadIdx.x;
  if (blk != 0) {
    float* xl = smem;
    float* wl = smem + 8192;
    const int eb = blk - 1;
    const int b = eb >> 8, ps = eb & 255;
    const float* xg = x + (size_t)b * CIN * HW + ps * 64;
#pragma unroll
    for (int j = 0; j < 8; ++j) {
      const int fj = j * 256 + tid;
      const int c = fj >> 4, q4 = (fj & 15) * 4;
      *(float4*)&xl[c * 64 + q4] = *(const float4*)(xg + (size_t)c * HW + q4);
      *(float4*)&wl[c * 64 + q4] = *(const float4*)(Wft + c * 64 + q4);
    }
    __syncthreads();
    const int px_grp = tid & 15, o_grp = tid >> 4;
    const int px = ps * 64 + px_grp * 4, o0 = o_grp * 4;
    float acc[16];
#pragma unroll
    for (int j = 0; j < 16; ++j) acc[j] = 0.f;
#pragma unroll 8
    for (int c = 0; c < 128; ++c) {
      const float4 xv = *(const float4*)&xl[c * 64 + px_grp * 4];
      const float4 wv = *(const float4*)&wl[c * 64 + o0];
      FMA16();
    }
    unsigned short* xtu = (unsigned short*)(ws + OFF_XT);
#pragma unroll
    for (int oj = 0; oj < 4; ++oj) {
      ushort4 u;
      u.x = f2bfu(acc[oj*4+0]); u.y = f2bfu(acc[oj*4+1]);
      u.z = f2bfu(acc[oj*4+2]); u.w = f2bfu(acc[oj*4+3]);
      *(ushort4*)(xtu + (size_t)(b * 64 + o0 + oj) * HW + px) = u;
    }
    const int4 kv = *(const int4*)(index + b * HW + px);
    const int kk[4] = {kv.x, kv.y, kv.z, kv.w};
    __syncthreads();
    float* bins = smem;
    float* cnt  = smem + 64 * 68;
    for (int i = tid; i < 64 * 68 + 64; i += 256) smem[i] = 0.f;
    __syncthreads();
#pragma unroll
    for (int pj = 0; pj < 4; ++pj) {
      const int kb = kk[pj] * 68 + o0;
      atomicAdd(&bins[kb    ], acc[ 0 + pj]);
      atomicAdd(&bins[kb + 1], acc[ 4 + pj]);
      atomicAdd(&bins[kb + 2], acc[ 8 + pj]);
      atomicAdd(&bins[kb + 3], acc[12 + pj]);
    }
    if (o_grp == 0) {
#pragma unroll
      for (int pj = 0; pj < 4; ++pj) atomicAdd(&cnt[kk[pj]], 1.f);
    }
    __syncthreads();
    unsigned short* pb = (unsigned short*)(ws + OFF_PS) + (size_t)eb * 4096;
    {
      const int k = tid >> 2, ob = (tid & 3) * 16;
#pragma unroll
      for (int q = 0; q < 4; ++q) {
        const float4 v = *(const float4*)&bins[k * 68 + ob + q * 4];
        ushort4 u;
        u.x = f2bfu(v.x); u.y = f2bfu(v.y); u.z = f2bfu(v.z); u.w = f2bfu(v.w);
        *(ushort4*)(pb + k * 64 + ob + q * 4) = u;
      }
    }
    if (tid < 64) ws[OFF_PC + (size_t)(b * 64 + tid) * 256 + ps] = cnt[tid];
  } else {
    float* wm = smem;
    float* Rb = smem + 8192;
    float* Cb = smem + 8704;
    for (int e = tid; e < 4096; e += 256) wm[(e >> 6) * 68 + (e & 63)] = Wm[e];
    __syncthreads();
    const int ig = tid >> 4, jg = tid & 15;
    const int i0 = ig << 2, j0 = jg << 2;
    float c4[16];
#pragma unroll
    for (int q = 0; q < 16; ++q) c4[q] = 0.f;
    for (int cq = 0; cq < 64; cq += 4) {
      float4 a[4], bb[4];
#pragma unroll
      for (int ii = 0; ii < 4; ++ii) a[ii]  = *(const float4*)&wm[(i0+ii)*68 + cq];
#pragma unroll
      for (int jj = 0; jj < 4; ++jj) bb[jj] = *(const float4*)&wm[(j0+jj)*68 + cq];
#pragma unroll
      for (int ii = 0; ii < 4; ++ii)
#pragma unroll
        for (int jj = 0; jj < 4; ++jj)
          c4[ii*4+jj] = fmaf(a[ii].x, bb[jj].x, fmaf(a[ii].y, bb[jj].y,
                        fmaf(a[ii].z, bb[jj].z, fmaf(a[ii].w, bb[jj].w, c4[ii*4+jj]))));
    }
    __syncthreads();
    __builtin_amdgcn_s_setprio(3);
    int buf = 0;
#pragma unroll 1
    for (int p = 0; p < 16; ++p) {
      const int P = p << 2;
      float* Rp = Rb + buf * 256;
      float* Cp = Cb + buf * 256;
      if (ig == p) {
#pragma unroll
        for (int r = 0; r < 4; ++r) {
          float4 t; t.x = c4[r*4+0]; t.y = c4[r*4+1]; t.z = c4[r*4+2]; t.w = c4[r*4+3];
          *(float4*)&Rp[r * 64 + j0] = t;
        }
      }
      if (jg == p) {
#pragma unroll
        for (int ii = 0; ii < 4; ++ii) {
          float4 t; t.x = c4[ii*4+0]; t.y = c4[ii*4+1]; t.z = c4[ii*4+2]; t.w = c4[ii*4+3];
          *(float4*)&Cp[(i0 + ii) * 4] = t;
        }
      }
      __syncthreads();
      float dd[16], cc[16], rr[16];
#pragma unroll
      for (int r = 0; r < 4; ++r) *(float4*)&dd[r * 4] = *(const float4*)&Rp[r * 64 + P];
#pragma unroll
      for (int ii = 0; ii < 4; ++ii) *(float4*)&cc[ii * 4] = *(const float4*)&Cp[(i0 + ii) * 4];
#pragma unroll
      for (int r = 0; r < 4; ++r) *(float4*)&rr[r * 4] = *(const float4*)&Rp[r * 64 + j0];
#pragma unroll
      for (int k = 0; k < 4; ++k) {
        const float rp = __builtin_amdgcn_rcpf(dd[k * 4 + k]);
        float ai[4], s[4];
#pragma unroll
        for (int j = 0; j < 4; ++j) s[j] = dd[k * 4 + j];
#pragma unroll
        for (int i = 0; i < 4; ++i) ai[i] = (i == k) ? (rp - 1.0f) : (-dd[i * 4 + k] * rp);
#pragma unroll
        for (int i = 0; i < 4; ++i)
#pragma unroll
          for (int j = 0; j < 4; ++j) dd[i * 4 + j] = fmaf(ai[i], s[j], dd[i * 4 + j]);
#pragma unroll
        for (int i = 0; i < 4; ++i) dd[i * 4 + k] = (i == k) ? rp : ai[i];
      }
      float T[16];
#pragma unroll
      for (int ii = 0; ii < 4; ++ii)
#pragma unroll
        for (int c = 0; c < 4; ++c) {
          float t = cc[ii*4+0] * dd[0*4+c];
          t = fmaf(cc[ii*4+1], dd[1*4+c], t);
          t = fmaf(cc[ii*4+2], dd[2*4+c], t);
          t = fmaf(cc[ii*4+3], dd[3*4+c], t);
          T[ii*4+c] = t;
        }
      if (ig == p && jg == p) {
#pragma unroll
        for (int q = 0; q < 16; ++q) c4[q] = dd[q];
      } else if (ig == p) {
#pragma unroll
        for (int r = 0; r < 4; ++r)
#pragma unroll
          for (int jj = 0; jj < 4; ++jj) {
            float t = dd[r*4+0] * rr[0*4+jj];
            t = fmaf(dd[r*4+1], rr[1*4+jj], t);
            t = fmaf(dd[r*4+2], rr[2*4+jj], t);
            t = fmaf(dd[r*4+3], rr[3*4+jj], t);
            c4[r*4+jj] = t;
          }
      } else if (jg == p) {
#pragma unroll
        for (int q = 0; q < 16; ++q) c4[q] = -T[q];
      } else {
#pragma unroll
        for (int ii = 0; ii < 4; ++ii)
#pragma unroll
          for (int jj = 0; jj < 4; ++jj) {
            float t = c4[ii*4+jj];
            t = fmaf(-T[ii*4+0], rr[0*4+jj], t);
            t = fmaf(-T[ii*4+1], rr[1*4+jj], t);
            t = fmaf(-T[ii*4+2], rr[2*4+jj], t);
            t = fmaf(-T[ii*4+3], rr[3*4+jj], t);
            c4[ii*4+jj] = t;
          }
      }
      buf ^= 1;
    }
    __builtin_amdgcn_s_setprio(0);
#pragma unroll
    for (int ii = 0; ii < 4; ++ii)
#pragma unroll
      for (int jj = 0; jj < 4; ++jj)
        ws[OFF_INV + (size_t)(i0 + ii) * 64 + j0 + jj] = c4[ii*4+jj];
  }
}

__global__ __launch_bounds__(1024) void k15_means_diag(float* __restrict__ ws)
{
  __shared__ float red[1024];
  __shared__ float lds_c[4];
  __shared__ float lds_m[64];
  const int blk = blockIdx.x, t = threadIdx.x;
  const int b = blk >> 6, k = blk & 63;
  const int o = t & 63, chunk = t >> 6;
  const unsigned short* psu = (const unsigned short*)(ws + OFF_PS);
  float s = 0.f;
#pragma unroll
  for (int i = 0; i < 16; ++i) {
    const int slab = chunk * 16 + i;
    s += bf2f(psu[(size_t)(b * 256 + slab) * 4096 + k * 64 + o]);
  }
  red[chunk * 64 + o] = s;
  float cv = 0.f;
  if (t < 256) cv = ws[OFF_PC + (size_t)(b * 64 + k) * 256 + t];
#pragma unroll
  for (int m = 32; m; m >>= 1) cv += __shfl_xor(cv, m, 64);
  if (t < 256 && (t & 63) == 0) lds_c[t >> 6] = cv;
  __syncthreads();
  if (t < 64) {
    float m_raw = 0.f;
#pragma unroll
    for (int ch = 0; ch < 16; ++ch) m_raw += red[ch * 64 + o];
    const float cnt = lds_c[0] + lds_c[1] + lds_c[2] + lds_c[3];
    const float denom = cnt + ((cnt == 0.f) ? 1.f : 0.f);
    const float m = m_raw / denom;
    ws[OFF_MEANS + (size_t)(b * 64 + k) * 64 + o] = m;
    lds_m[o] = m;
    float inner = 0.f;
#pragma unroll 8
    for (int d = 0; d < 64; ++d) inner = fmaf(ws[OFF_INV + d * 64 + o], lds_m[d], inner);
    float p = m * inner;
#pragma unroll
    for (int mm = 32; mm; mm >>= 1) p += __shfl_xor(p, mm, 64);
    if (o == 0) ws[OFF_DIAG + b * 64 + k] = p;
  }
}

__global__ __launch_bounds__(256) void k2_adj(float* __restrict__ ws)
{
  __shared__ __align__(16) float means_s[64 * 68];
  __shared__ __align__(16) float inv_s[64 * 68];
  __shared__ __align__(16) float T_s[8 * 68];
  __shared__ __align__(16) float adj_s[8 * 68];
  __shared__ float diag_s[64];
  const int b = blockIdx.x >> 3;
  const int i0 = (blockIdx.x & 7) << 3;
  const int t = threadIdx.x;
  const float* mg = ws + OFF_MEANS + b * 4096;
  for (int e = t; e < 4096; e += 256) means_s[(e >> 6) * 68 + (e & 63)] = mg[e];
  const float* ig = ws + OFF_INV;
  for (int e = t; e < 4096; e += 256) inv_s[(e >> 6) * 68 + (e & 63)] = ig[e];
  if (t < 64) diag_s[t] = ws[OFF_DIAG + b * 64 + t];
  __syncthreads();
  if (t < 128) {
    const int i = t >> 4, d0 = (t & 15) << 2;
    float4 acc = {0.f, 0.f, 0.f, 0.f};
    for (int c = 0; c < 64; ++c) {
      const float mv = means_s[(i0 + i) * 68 + c];
      const float4 iv = *(const float4*)&inv_s[c * 68 + d0];
      acc.x = fmaf(mv, iv.x, acc.x); acc.y = fmaf(mv, iv.y, acc.y);
      acc.z = fmaf(mv, iv.z, acc.z); acc.w = fmaf(mv, iv.w, acc.w);
    }
    *(float4*)&T_s[i * 68 + d0] = acc;
  }
  __syncthreads();
  {
    const int i = t >> 5, jb = t & 31;
#pragma unroll
    for (int jj = 0; jj < 2; ++jj) {
      const int j = jb + (jj << 5);
      float4 p4 = {0.f, 0.f, 0.f, 0.f};
      for (int dq = 0; dq < 64; dq += 4) {
        const float4 tv = *(const float4*)&T_s[i * 68 + dq];
        const float4 mv = *(const float4*)&means_s[j * 68 + dq];
        p4.x = fmaf(tv.x, mv.x, p4.x); p4.y = fmaf(tv.y, mv.y, p4.y);
        p4.z = fmaf(tv.z, mv.z, p4.z); p4.w = fmaf(tv.w, mv.w, p4.w);
      }
      const float p = (p4.x + p4.y) + (p4.z + p4.w);
      const float q = diag_s[i0 + i] + diag_s[j] - 2.f * p;
      adj_s[i * 68 + j] = __expf(-sqrtf(fmaxf(q, 1e-12f)));
    }
  }
  __syncthreads();
  if (t < 128) {
    const int i = t >> 4, oq = (t & 15) << 2;
    float4 am = {0.f, 0.f, 0.f, 0.f};
    for (int j = 0; j < 64; ++j) {
      const float av = adj_s[i * 68 + j];
      const float4 mv = *(const float4*)&means_s[j * 68 + oq];
      am.x = fmaf(av, mv.x, am.x); am.y = fmaf(av, mv.y, am.y);
      am.z = fmaf(av, mv.z, am.z); am.w = fmaf(av, mv.w, am.w);
    }
    *(float4*)(ws + OFF_ADJM + (size_t)(b * 64 + i0 + i) * 64 + oq) = am;
  }
}

__global__ __launch_bounds__(256) void k3_bnstats(const int* __restrict__ index,
                                                  float* __restrict__ ws)
{
  __shared__ float am_s[128];
  __shared__ float red[4];
  const int blk = blockIdx.x, t = threadIdx.x;
  const int b = blk >> 8, oc = (blk >> 3) & 31, tile = blk & 7;
  const int o0 = oc * 2;
  if (t < 128) am_s[t] = ws[OFF_ADJM + (size_t)(b * 64 + (t >> 1)) * 64 + o0 + (t & 1)];
  if (t < 4) red[t] = 0.f;
  __syncthreads();
  const int lane = t & 63, w = t >> 6;
  const unsigned short* xtu = (const unsigned short*)(ws + OFF_XT);
  float s0 = 0.f, s1 = 0.f, q0 = 0.f, q1 = 0.f;
#pragma unroll
  for (int q = 0; q < 2; ++q) {
    const int px = tile * 2048 + (w * 2 + q) * 256 + lane * 4;
    const int4 kv = *(const int4*)(index + b * HW + px);
    const ushort4 u0 = *(const ushort4*)(xtu + (size_t)(b * 64 + o0    ) * HW + px);
    const ushort4 u1 = *(const ushort4*)(xtu + (size_t)(b * 64 + o0 + 1) * HW + px);
    const int kk[4] = {kv.x, kv.y, kv.z, kv.w};
    const float x0[4] = {bf2f(u0.x), bf2f(u0.y), bf2f(u0.z), bf2f(u0.w)};
    const float x1[4] = {bf2f(u1.x), bf2f(u1.y), bf2f(u1.z), bf2f(u1.w)};
#pragma unroll
    for (int j = 0; j < 4; ++j) {
      const float2 am = *(const float2*)&am_s[kk[j] * 2];
      const float f0 = fmaxf(x0[j] + am.x, 0.f);
      const float f1 = fmaxf(x1[j] + am.y, 0.f);
      s0 += f0; q0 = fmaf(f0, f0, q0);
      s1 += f1; q1 = fmaf(f1, f1, q1);
    }
  }
#pragma unroll
  for (int m = 1; m < 64; m <<= 1) {
    s0 += __shfl_xor(s0, m, 64); s1 += __shfl_xor(s1, m, 64);
    q0 += __shfl_xor(q0, m, 64); q1 += __shfl_xor(q1, m, 64);
  }
  if (lane == 0) {
    atomicAdd(&red[0], s0); atomicAdd(&red[1], s1);
    atomicAdd(&red[2], q0); atomicAdd(&red[3], q1);
  }
  __syncthreads();
  if (t == 0) {
    float4 v; v.x = red[0]; v.y = red[1]; v.z = red[2]; v.w = red[3];
    *(float4*)(ws + OFF_BNP + (size_t)(oc * 16 + b * 8 + tile) * 4) = v;
  }
}

__global__ __launch_bounds__(256) void k4_out(const int* __restrict__ index,
    const float* __restrict__ gamma, const float* __restrict__ beta,
    const float* __restrict__ ws, float* __restrict__ out)
{
  __shared__ float am_s[128];
  __shared__ float4 tmp[16];
  __shared__ float sc_s[2], sh_s[2];
  const int blk = blockIdx.x, t = threadIdx.x;
  const int b = blk >> 8, oc = (blk >> 3) & 31, tile = blk & 7;
  const int o0 = oc * 2;
  if (t < 128) am_s[t] = ws[OFF_ADJM + (size_t)(b * 64 + (t >> 1)) * 64 + o0 + (t & 1)];
  if (t < 16) tmp[t] = *(const float4*)(ws + OFF_BNP + (size_t)(oc * 16 + t) * 4);
  if (t < 2) {
    float s = 0.f, qq = 0.f;
#pragma unroll
    for (int i = 0; i < 16; ++i) {
      const float4 v = tmp[i];
      s  += (t == 0) ? v.x : v.y;
      qq += (t == 0) ? v.z : v.w;
    }
    const float mean = s * (1.f / 32768.f);
    const float var  = qq * (1.f / 32768.f) - mean * mean;
    const float sc = gamma[o0 + t] * rsqrtf(var + 1e-5f);
    sc_s[t] = sc;
    sh_s[t] = fmaf(-mean, sc, beta[o0 + t]);
  }
  __syncthreads();
  const int lane = t & 63, w = t >> 6;
  const unsigned short* xtu = (const unsigned short*)(ws + OFF_XT);
  const float c0 = sc_s[0], c1 = sc_s[1], h0 = sh_s[0], h1 = sh_s[1];
#pragma unroll
  for (int q = 0; q < 2; ++q) {
    const int px = tile * 2048 + (w * 2 + q) * 256 + lane * 4;
    const int4 kv = *(const int4*)(index + b * HW + px);
    const ushort4 u0 = *(const ushort4*)(xtu + (size_t)(b * 64 + o0    ) * HW + px);
    const ushort4 u1 = *(const ushort4*)(xtu + (size_t)(b * 64 + o0 + 1) * HW + px);
    const int kk[4] = {kv.x, kv.y, kv.z, kv.w};
    const float x0[4] = {bf2f(u0.x), bf2f(u0.y), bf2f(u0.z), bf2f(u0.w)};
    const float x1[4] = {bf2f(u1.x), bf2f(u1.y), bf2f(u1.z), bf2f(u1.w)};
    float4 o4a, o4b;
    float* oa = (float*)&o4a; float* ob = (float*)&o4b;
#pragma unroll
    for (int j = 0; j < 4; ++j) {
      const float2 am = *(const float2*)&am_s[kk[j] * 2];
      oa[j] = fmaf(fmaxf(x0[j] + am.x, 0.f), c0, h0);
      ob[j] = fmaf(fmaxf(x1[j] + am.y, 0.f), c1, h1);
    }
    *(float4*)(out + (size_t)(b * 64 + o0    ) * HW + px) = o4a;
    *(float4*)(out + (size_t)(b * 64 + o0 + 1) * HW + px) = o4b;
  }
}

extern "C" void kernel_launch(void* const* d_in, const int* in_sizes, int n_in,
                              void* d_out, int out_size, void* d_ws, size_t ws_size,
                              hipStream_t stream) {
  const float* x     = (const float*)d_in[0];
  const int*   index = (const int*)d_in[1];
  const float* Wft   = (const float*)d_in[2];
  const float* Wm    = (const float*)d_in[3];
  const float* gamma = (const float*)d_in[4];
  const float* beta  = (const float*)d_in[5];
  float* ws  = (float*)d_ws;
  float* out = (float*)d_out;

  void* params[] = {(void*)&x, (void*)&index, (void*)&Wft, (void*)&Wm,
                    (void*)&gamma, (void*)&beta, (void*)&ws, (void*)&out};
  hipError_t err = hipLaunchCooperativeKernel(fused_gnn, dim3(512), dim3(256),
                                              params, 0u, stream);
  if (err != hipSuccess) {
    // Fallback: proven 5-kernel pipeline (baseline ~121 us)
    k1_xt_bins_inv<<<513, 256, 0, stream>>>(x, index, Wft, Wm, ws);
    k15_means_diag<<<128, 1024, 0, stream>>>(ws);
    k2_adj<<<16, 256, 0, stream>>>(ws);
    k3_bnstats<<<512, 256, 0, stream>>>(index, ws);
    k4_out<<<512, 256, 0, stream>>>(index, gamma, beta, ws, out);
  }
}

// Round 2
// 253.897 us; speedup vs baseline: 1.3609x; 1.3609x over previous
//
#include <hip/hip_runtime.h>
#include <hip/hip_bf16.h>

// Problem constants
#define CIN   128
#define COUT  64
#define HW    16384   // 128*128

typedef __hip_bfloat16 bf16;

// Workspace layout (float offsets) — identical to proven 121us baseline
#define OFF_XT    0u          // bf16[2][64][16384]  xt
#define OFF_PS    1048576u    // bf16[512 blk][64 k][64 o] partial bin sums
#define OFF_PC    2097152u    // f32 [2][64][256]    partial bin counts
#define OFF_MEANS 2129920u    // f32 [2][64][64]
#define OFF_DIAG  2138112u    // f32 [2][64]         (unused in this version)
#define OFF_INV   2138240u    // f32 [64][64]        inv(cov)
#define OFF_ADJM  2142336u    // f32 [2][64][64]     adj @ means
#define OFF_BNP   2150528u    // f32 [32 oc][16 b*tile] float4 {s0,s1,ss0,ss1}
// sync counters live in out[0..1] (zeroed by K1, overwritten by K4) — ws layout untouched

__device__ __forceinline__ unsigned short f2bfu(float f) {
  union { bf16 h; unsigned short u; } cv; cv.h = __float2bfloat16(f); return cv.u;
}
__device__ __forceinline__ float bf2f(unsigned short u) {
  union { unsigned int i; float f; } cv; cv.i = ((unsigned int)u) << 16; return cv.f;
}

#define FMA16() do { \
  acc[ 0]=fmaf(xv.x,wv.x,acc[ 0]); acc[ 1]=fmaf(xv.y,wv.x,acc[ 1]); \
  acc[ 2]=fmaf(xv.z,wv.x,acc[ 2]); acc[ 3]=fmaf(xv.w,wv.x,acc[ 3]); \
  acc[ 4]=fmaf(xv.x,wv.y,acc[ 4]); acc[ 5]=fmaf(xv.y,wv.y,acc[ 5]); \
  acc[ 6]=fmaf(xv.z,wv.y,acc[ 6]); acc[ 7]=fmaf(xv.w,wv.y,acc[ 7]); \
  acc[ 8]=fmaf(xv.x,wv.z,acc[ 8]); acc[ 9]=fmaf(xv.y,wv.z,acc[ 9]); \
  acc[10]=fmaf(xv.z,wv.z,acc[10]); acc[11]=fmaf(xv.w,wv.z,acc[11]); \
  acc[12]=fmaf(xv.x,wv.w,acc[12]); acc[13]=fmaf(xv.y,wv.w,acc[13]); \
  acc[14]=fmaf(xv.z,wv.w,acc[14]); acc[15]=fmaf(xv.w,wv.w,acc[15]); \
} while (0)

// ============================================================================
// K1: xt = einsum (bf16 out) + per-block bin partials; block 0 = inv(Wm Wm^T)
// and zeroes the sync counters. Verbatim proven baseline otherwise.
// ============================================================================
__global__ __launch_bounds__(256, 2) void k1_xt_bins_inv(
    const float* __restrict__ x, const int* __restrict__ index,
    const float* __restrict__ Wft, const float* __restrict__ Wm,
    float* __restrict__ ws, unsigned* __restrict__ cnt)
{
  __shared__ __align__(16) float smem[16384];   // 64 KB
  const int blk = blockIdx.x, tid = threadIdx.x;
  if (blk != 0) {
    float* xl = smem;          // [128 c][64 px]
    float* wl = smem + 8192;   // [128 c][64 o]
    const int eb = blk - 1;
    const int b = eb >> 8, ps = eb & 255;
    const float* xg = x + (size_t)b * CIN * HW + ps * 64;
#pragma unroll
    for (int j = 0; j < 8; ++j) {
      const int fj = j * 256 + tid;
      const int c = fj >> 4, q4 = (fj & 15) * 4;
      *(float4*)&xl[c * 64 + q4] = *(const float4*)(xg + (size_t)c * HW + q4);
      *(float4*)&wl[c * 64 + q4] = *(const float4*)(Wft + c * 64 + q4);
    }
    __syncthreads();
    const int px_grp = tid & 15, o_grp = tid >> 4;
    const int px = ps * 64 + px_grp * 4, o0 = o_grp * 4;
    float acc[16];
#pragma unroll
    for (int j = 0; j < 16; ++j) acc[j] = 0.f;
#pragma unroll 8
    for (int c = 0; c < 128; ++c) {
      const float4 xv = *(const float4*)&xl[c * 64 + px_grp * 4];
      const float4 wv = *(const float4*)&wl[c * 64 + o0];
      FMA16();
    }
    unsigned short* xtu = (unsigned short*)(ws + OFF_XT);
#pragma unroll
    for (int oj = 0; oj < 4; ++oj) {
      ushort4 u;
      u.x = f2bfu(acc[oj*4+0]); u.y = f2bfu(acc[oj*4+1]);
      u.z = f2bfu(acc[oj*4+2]); u.w = f2bfu(acc[oj*4+3]);
      *(ushort4*)(xtu + (size_t)(b * 64 + o0 + oj) * HW + px) = u;
    }
    const int4 kv = *(const int4*)(index + b * HW + px);
    const int kk[4] = {kv.x, kv.y, kv.z, kv.w};
    __syncthreads();
    float* bins = smem;
    float* cnt_s = smem + 64 * 68;
    for (int i = tid; i < 64 * 68 + 64; i += 256) smem[i] = 0.f;
    __syncthreads();
#pragma unroll
    for (int pj = 0; pj < 4; ++pj) {
      const int kb = kk[pj] * 68 + o0;
      atomicAdd(&bins[kb    ], acc[ 0 + pj]);
      atomicAdd(&bins[kb + 1], acc[ 4 + pj]);
      atomicAdd(&bins[kb + 2], acc[ 8 + pj]);
      atomicAdd(&bins[kb + 3], acc[12 + pj]);
    }
    if (o_grp == 0) {
#pragma unroll
      for (int pj = 0; pj < 4; ++pj) atomicAdd(&cnt_s[kk[pj]], 1.f);
    }
    __syncthreads();
    unsigned short* pb = (unsigned short*)(ws + OFF_PS) + (size_t)eb * 4096;
    {
      const int k = tid >> 2, ob = (tid & 3) * 16;
#pragma unroll
      for (int q = 0; q < 4; ++q) {
        const float4 v = *(const float4*)&bins[k * 68 + ob + q * 4];
        ushort4 u;
        u.x = f2bfu(v.x); u.y = f2bfu(v.y); u.z = f2bfu(v.z); u.w = f2bfu(v.w);
        *(ushort4*)(pb + k * 64 + ob + q * 4) = u;
      }
    }
    if (tid < 64) ws[OFF_PC + (size_t)(b * 64 + tid) * 256 + ps] = cnt_s[tid];
  } else {
    if (tid == 0) { cnt[0] = 0u; cnt[1] = 0u; }   // sync counters for kmid
    // inverse block: blocked Gauss-Jordan, 16 panels of 4 pivots (proven form)
    float* wm = smem;
    float* Rb = smem + 8192;
    float* Cb = smem + 8704;
    for (int e = tid; e < 4096; e += 256) wm[(e >> 6) * 68 + (e & 63)] = Wm[e];
    __syncthreads();
    const int ig = tid >> 4, jg = tid & 15;
    const int i0 = ig << 2, j0 = jg << 2;
    float c4[16];
#pragma unroll
    for (int q = 0; q < 16; ++q) c4[q] = 0.f;
    for (int cq = 0; cq < 64; cq += 4) {
      float4 a[4], bb[4];
#pragma unroll
      for (int ii = 0; ii < 4; ++ii) a[ii]  = *(const float4*)&wm[(i0+ii)*68 + cq];
#pragma unroll
      for (int jj = 0; jj < 4; ++jj) bb[jj] = *(const float4*)&wm[(j0+jj)*68 + cq];
#pragma unroll
      for (int ii = 0; ii < 4; ++ii)
#pragma unroll
        for (int jj = 0; jj < 4; ++jj)
          c4[ii*4+jj] = fmaf(a[ii].x, bb[jj].x, fmaf(a[ii].y, bb[jj].y,
                        fmaf(a[ii].z, bb[jj].z, fmaf(a[ii].w, bb[jj].w, c4[ii*4+jj]))));
    }
    __syncthreads();
    __builtin_amdgcn_s_setprio(3);
    int buf = 0;
#pragma unroll 1   // MUST stay rolled (I$ thrash)
    for (int p = 0; p < 16; ++p) {
      const int P = p << 2;
      float* Rp = Rb + buf * 256;
      float* Cp = Cb + buf * 256;
      if (ig == p) {
#pragma unroll
        for (int r = 0; r < 4; ++r) {
          float4 t; t.x = c4[r*4+0]; t.y = c4[r*4+1]; t.z = c4[r*4+2]; t.w = c4[r*4+3];
          *(float4*)&Rp[r * 64 + j0] = t;
        }
      }
      if (jg == p) {
#pragma unroll
        for (int ii = 0; ii < 4; ++ii) {
          float4 t; t.x = c4[ii*4+0]; t.y = c4[ii*4+1]; t.z = c4[ii*4+2]; t.w = c4[ii*4+3];
          *(float4*)&Cp[(i0 + ii) * 4] = t;
        }
      }
      __syncthreads();
      float dd[16], cc[16], rr[16];
#pragma unroll
      for (int r = 0; r < 4; ++r) *(float4*)&dd[r * 4] = *(const float4*)&Rp[r * 64 + P];
#pragma unroll
      for (int ii = 0; ii < 4; ++ii) *(float4*)&cc[ii * 4] = *(const float4*)&Cp[(i0 + ii) * 4];
#pragma unroll
      for (int r = 0; r < 4; ++r) *(float4*)&rr[r * 4] = *(const float4*)&Rp[r * 64 + j0];
#pragma unroll
      for (int k = 0; k < 4; ++k) {
        const float rp = __builtin_amdgcn_rcpf(dd[k * 4 + k]);
        float ai[4], s[4];
#pragma unroll
        for (int j = 0; j < 4; ++j) s[j] = dd[k * 4 + j];
#pragma unroll
        for (int i = 0; i < 4; ++i) ai[i] = (i == k) ? (rp - 1.0f) : (-dd[i * 4 + k] * rp);
#pragma unroll
        for (int i = 0; i < 4; ++i)
#pragma unroll
          for (int j = 0; j < 4; ++j) dd[i * 4 + j] = fmaf(ai[i], s[j], dd[i * 4 + j]);
#pragma unroll
        for (int i = 0; i < 4; ++i) dd[i * 4 + k] = (i == k) ? rp : ai[i];
      }
      float T[16];
#pragma unroll
      for (int ii = 0; ii < 4; ++ii)
#pragma unroll
        for (int c = 0; c < 4; ++c) {
          float t = cc[ii*4+0] * dd[0*4+c];
          t = fmaf(cc[ii*4+1], dd[1*4+c], t);
          t = fmaf(cc[ii*4+2], dd[2*4+c], t);
          t = fmaf(cc[ii*4+3], dd[3*4+c], t);
          T[ii*4+c] = t;
        }
      if (ig == p && jg == p) {
#pragma unroll
        for (int q = 0; q < 16; ++q) c4[q] = dd[q];
      } else if (ig == p) {
#pragma unroll
        for (int r = 0; r < 4; ++r)
#pragma unroll
          for (int jj = 0; jj < 4; ++jj) {
            float t = dd[r*4+0] * rr[0*4+jj];
            t = fmaf(dd[r*4+1], rr[1*4+jj], t);
            t = fmaf(dd[r*4+2], rr[2*4+jj], t);
            t = fmaf(dd[r*4+3], rr[3*4+jj], t);
            c4[r*4+jj] = t;
          }
      } else if (jg == p) {
#pragma unroll
        for (int q = 0; q < 16; ++q) c4[q] = -T[q];
      } else {
#pragma unroll
        for (int ii = 0; ii < 4; ++ii)
#pragma unroll
          for (int jj = 0; jj < 4; ++jj) {
            float t = c4[ii*4+jj];
            t = fmaf(-T[ii*4+0], rr[0*4+jj], t);
            t = fmaf(-T[ii*4+1], rr[1*4+jj], t);
            t = fmaf(-T[ii*4+2], rr[2*4+jj], t);
            t = fmaf(-T[ii*4+3], rr[3*4+jj], t);
            c4[ii*4+jj] = t;
          }
      }
      buf ^= 1;
    }
    __builtin_amdgcn_s_setprio(0);
#pragma unroll
    for (int ii = 0; ii < 4; ++ii)
#pragma unroll
      for (int jj = 0; jj < 4; ++jj)
        ws[OFF_INV + (size_t)(i0 + ii) * 64 + j0 + jj] = c4[ii*4+jj];
  }
}

// ============================================================================
// KMID: merged K15+K2+K3 with intra-kernel partial-grid handshakes.
//   blk 0..127 : means (producer, cnt[0])
//   blk 128..143: adj+adjm after cnt[0]==128 (producer, cnt[1])
//   all 512    : BN partial stats after cnt[1]==16 (inputs preloaded to regs
//                before polling, so HBM latency hides under the wait)
// Capacity: 39.4 KB LDS, 256 thr -> 4 blocks/CU * 256 CU = 1024 >= 512, so
// all blocks co-resident; spin waits are deadlock-free by capacity.
// ============================================================================
__global__ __launch_bounds__(256) void kmid(const int* __restrict__ index,
                                            float* __restrict__ ws,
                                            unsigned* __restrict__ cnt)
{
  __shared__ __align__(16) float smem[9856];   // 39.4 KB (adj branch is the max)
  const int blk = blockIdx.x, tid = threadIdx.x;

  // ---- stats identity + register preload (ALL blocks, before any waiting)
  const int sb = blk >> 8, oc = (blk >> 3) & 31, tile = blk & 7;
  const int o0s = oc * 2;
  const int lane = tid & 63, w = tid >> 6;
  const unsigned short* xtu = (const unsigned short*)(ws + OFF_XT);
  int4 kvv[2]; ushort4 u0r[2], u1r[2];
#pragma unroll
  for (int q = 0; q < 2; ++q) {
    const int px = tile * 2048 + (w * 2 + q) * 256 + lane * 4;
    kvv[q] = *(const int4*)(index + sb * HW + px);
    u0r[q] = *(const ushort4*)(xtu + (size_t)(sb * 64 + o0s    ) * HW + px);
    u1r[q] = *(const ushort4*)(xtu + (size_t)(sb * 64 + o0s + 1) * HW + px);
  }

  if (blk < 128) {
    // ---------------- means (verified round-1 B1 body) ----------------
    const int bb = blk >> 6, k = blk & 63;
    float* red   = smem;           // [16][64]
    float* lds_c = smem + 1024;    // [4]
    const unsigned short* psu = (const unsigned short*)(ws + OFF_PS);
    const int o4 = (tid & 15) * 4, chunk = tid >> 4;
    float s4[4] = {0.f, 0.f, 0.f, 0.f};
#pragma unroll 4
    for (int i = 0; i < 16; ++i) {
      const int slab = chunk * 16 + i;
      const ushort4 u = *(const ushort4*)(psu + (size_t)(bb * 256 + slab) * 4096 + k * 64 + o4);
      s4[0] += bf2f(u.x); s4[1] += bf2f(u.y); s4[2] += bf2f(u.z); s4[3] += bf2f(u.w);
    }
#pragma unroll
    for (int j = 0; j < 4; ++j) red[chunk * 64 + o4 + j] = s4[j];
    float cv = ws[OFF_PC + (size_t)(bb * 64 + k) * 256 + tid];
#pragma unroll
    for (int m = 32; m; m >>= 1) cv += __shfl_xor(cv, m, 64);
    if ((tid & 63) == 0) lds_c[tid >> 6] = cv;
    __syncthreads();
    if (tid < 64) {
      float m_raw = 0.f;
#pragma unroll
      for (int ch = 0; ch < 16; ++ch) m_raw += red[ch * 64 + tid];
      const float cntv = lds_c[0] + lds_c[1] + lds_c[2] + lds_c[3];
      const float denom = cntv + ((cntv == 0.f) ? 1.f : 0.f);
      ws[OFF_MEANS + (size_t)(bb * 64 + k) * 64 + tid] = m_raw / denom;
    }
    __threadfence();
    __syncthreads();
    if (tid == 0)
      __hip_atomic_fetch_add(&cnt[0], 1u, __ATOMIC_RELEASE, __HIP_MEMORY_SCOPE_AGENT);
  } else if (blk < 144) {
    // ---------------- adj + adjm (verified round-1 B2 body) ----------------
    if (tid == 0) {
      while (__hip_atomic_load(&cnt[0], __ATOMIC_ACQUIRE, __HIP_MEMORY_SCOPE_AGENT) < 128u)
        __builtin_amdgcn_s_sleep(16);
    }
    __syncthreads();
    __threadfence();
    const int abl = blk - 128;
    const int bb = abl >> 3, r0 = (abl & 7) << 3;
    float* means_s = smem;            // [64][68]
    float* inv_s   = smem + 4352;     // [64][68]
    float* T_s     = smem + 8704;     // [8][68]
    float* adj_s   = smem + 9248;     // [8][68]
    float* d_s     = smem + 9792;     // [64]
    const float* mg = ws + OFF_MEANS + (size_t)bb * 4096;
    for (int e = tid; e < 4096; e += 256) means_s[(e >> 6) * 68 + (e & 63)] = mg[e];
    for (int e = tid; e < 4096; e += 256) inv_s[(e >> 6) * 68 + (e & 63)] = ws[OFF_INV + e];
    __syncthreads();
    {   // thread = (row j, 16-col strip): T[j][oq..oq+15], d_j partial
      const int j = tid >> 2, oq = (tid & 3) << 4;
      float4 Ta[4];
#pragma unroll
      for (int v = 0; v < 4; ++v) { Ta[v].x = 0.f; Ta[v].y = 0.f; Ta[v].z = 0.f; Ta[v].w = 0.f; }
      for (int c = 0; c < 64; ++c) {
        const float mv = means_s[j * 68 + c];
#pragma unroll
        for (int v = 0; v < 4; ++v) {
          const float4 iv = *(const float4*)&inv_s[c * 68 + oq + v * 4];
          Ta[v].x = fmaf(mv, iv.x, Ta[v].x); Ta[v].y = fmaf(mv, iv.y, Ta[v].y);
          Ta[v].z = fmaf(mv, iv.z, Ta[v].z); Ta[v].w = fmaf(mv, iv.w, Ta[v].w);
        }
      }
      float dp = 0.f;
#pragma unroll
      for (int v = 0; v < 4; ++v) {
        const float4 mvv = *(const float4*)&means_s[j * 68 + oq + v * 4];
        dp = fmaf(Ta[v].x, mvv.x, dp); dp = fmaf(Ta[v].y, mvv.y, dp);
        dp = fmaf(Ta[v].z, mvv.z, dp); dp = fmaf(Ta[v].w, mvv.w, dp);
      }
      dp += __shfl_xor(dp, 1, 64);
      dp += __shfl_xor(dp, 2, 64);
      if ((tid & 3) == 0) d_s[j] = dp;
      if (j >= r0 && j < r0 + 8) {
#pragma unroll
        for (int v = 0; v < 4; ++v) *(float4*)&T_s[(j - r0) * 68 + oq + v * 4] = Ta[v];
      }
    }
    __syncthreads();
    {   // q_ij = d_i + d_j - 2 T_i.m_j ; adj = exp(-sqrt(max(q,1e-12)))
      const int i = tid >> 5, jb = tid & 31;
#pragma unroll
      for (int jj = 0; jj < 2; ++jj) {
        const int jc = jb + (jj << 5);
        float4 p4 = {0.f, 0.f, 0.f, 0.f};
        for (int dq = 0; dq < 64; dq += 4) {
          const float4 tv = *(const float4*)&T_s[i * 68 + dq];
          const float4 mv = *(const float4*)&means_s[jc * 68 + dq];
          p4.x = fmaf(tv.x, mv.x, p4.x); p4.y = fmaf(tv.y, mv.y, p4.y);
          p4.z = fmaf(tv.z, mv.z, p4.z); p4.w = fmaf(tv.w, mv.w, p4.w);
        }
        const float p = (p4.x + p4.y) + (p4.z + p4.w);
        const float q = d_s[r0 + i] + d_s[jc] - 2.f * p;
        adj_s[i * 68 + jc] = __expf(-sqrtf(fmaxf(q, 1e-12f)));
      }
    }
    __syncthreads();
    if (tid < 128) {   // adjm rows
      const int i = tid >> 4, oq4 = (tid & 15) << 2;
      float4 am = {0.f, 0.f, 0.f, 0.f};
      for (int jc = 0; jc < 64; ++jc) {
        const float av = adj_s[i * 68 + jc];
        const float4 mv = *(const float4*)&means_s[jc * 68 + oq4];
        am.x = fmaf(av, mv.x, am.x); am.y = fmaf(av, mv.y, am.y);
        am.z = fmaf(av, mv.z, am.z); am.w = fmaf(av, mv.w, am.w);
      }
      *(float4*)(ws + OFF_ADJM + (size_t)(bb * 64 + r0 + i) * 64 + oq4) = am;
    }
    __threadfence();
    __syncthreads();
    if (tid == 0)
      __hip_atomic_fetch_add(&cnt[1], 1u, __ATOMIC_RELEASE, __HIP_MEMORY_SCOPE_AGENT);
  }

  // ---------------- all 512 blocks: wait for adjm, then BN stats ----------------
  if (tid == 0) {
    while (__hip_atomic_load(&cnt[1], __ATOMIC_ACQUIRE, __HIP_MEMORY_SCOPE_AGENT) < 16u)
      __builtin_amdgcn_s_sleep(16);
  }
  __syncthreads();
  __threadfence();
  {
    float* am_s = smem;          // [128]
    float* red4 = smem + 128;    // [4]
    if (tid < 128) am_s[tid] = ws[OFF_ADJM + (size_t)(sb * 64 + (tid >> 1)) * 64 + o0s + (tid & 1)];
    if (tid < 4) red4[tid] = 0.f;
    __syncthreads();
    float s0 = 0.f, s1 = 0.f, q0 = 0.f, q1 = 0.f;
#pragma unroll
    for (int q = 0; q < 2; ++q) {
      const int kk[4] = {kvv[q].x, kvv[q].y, kvv[q].z, kvv[q].w};
      const float x0[4] = {bf2f(u0r[q].x), bf2f(u0r[q].y), bf2f(u0r[q].z), bf2f(u0r[q].w)};
      const float x1[4] = {bf2f(u1r[q].x), bf2f(u1r[q].y), bf2f(u1r[q].z), bf2f(u1r[q].w)};
#pragma unroll
      for (int j = 0; j < 4; ++j) {
        const float2 am = *(const float2*)&am_s[kk[j] * 2];
        const float f0 = fmaxf(x0[j] + am.x, 0.f);
        const float f1 = fmaxf(x1[j] + am.y, 0.f);
        s0 += f0; q0 = fmaf(f0, f0, q0);
        s1 += f1; q1 = fmaf(f1, f1, q1);
      }
    }
#pragma unroll
    for (int m = 1; m < 64; m <<= 1) {
      s0 += __shfl_xor(s0, m, 64); s1 += __shfl_xor(s1, m, 64);
      q0 += __shfl_xor(q0, m, 64); q1 += __shfl_xor(q1, m, 64);
    }
    if (lane == 0) {
      atomicAdd(&red4[0], s0); atomicAdd(&red4[1], s1);
      atomicAdd(&red4[2], q0); atomicAdd(&red4[3], q1);
    }
    __syncthreads();
    if (tid == 0) {
      float4 v; v.x = red4[0]; v.y = red4[1]; v.z = red4[2]; v.w = red4[3];
      *(float4*)(ws + OFF_BNP + (size_t)(oc * 16 + sb * 8 + tile) * 4) = v;
    }
  }
}

// ============================================================================
// K4: redundant BN-final reduce (16 float4) per block, then out = f*scale+shift.
// Verbatim proven baseline. Overwrites the counter bytes at out[0..1].
// ============================================================================
__global__ __launch_bounds__(256) void k4_out(const int* __restrict__ index,
    const float* __restrict__ gamma, const float* __restrict__ beta,
    const float* __restrict__ ws, float* __restrict__ out)
{
  __shared__ float am_s[128];
  __shared__ float4 tmp[16];
  __shared__ float sc_s[2], sh_s[2];
  const int blk = blockIdx.x, t = threadIdx.x;
  const int b = blk >> 8, oc = (blk >> 3) & 31, tile = blk & 7;
  const int o0 = oc * 2;
  if (t < 128) am_s[t] = ws[OFF_ADJM + (size_t)(b * 64 + (t >> 1)) * 64 + o0 + (t & 1)];
  if (t < 16) tmp[t] = *(const float4*)(ws + OFF_BNP + (size_t)(oc * 16 + t) * 4);
  if (t < 2) {   // same wave as tmp writers: per-wave LDS ordering suffices
    float s = 0.f, qq = 0.f;
#pragma unroll
    for (int i = 0; i < 16; ++i) {
      const float4 v = tmp[i];
      s  += (t == 0) ? v.x : v.y;
      qq += (t == 0) ? v.z : v.w;
    }
    const float mean = s * (1.f / 32768.f);
    const float var  = qq * (1.f / 32768.f) - mean * mean;
    const float sc = gamma[o0 + t] * rsqrtf(var + 1e-5f);
    sc_s[t] = sc;
    sh_s[t] = fmaf(-mean, sc, beta[o0 + t]);
  }
  __syncthreads();
  const int lane = t & 63, w = t >> 6;
  const unsigned short* xtu = (const unsigned short*)(ws + OFF_XT);
  const float c0 = sc_s[0], c1 = sc_s[1], h0 = sh_s[0], h1 = sh_s[1];
#pragma unroll
  for (int q = 0; q < 2; ++q) {
    const int px = tile * 2048 + (w * 2 + q) * 256 + lane * 4;
    const int4 kv = *(const int4*)(index + b * HW + px);
    const ushort4 u0 = *(const ushort4*)(xtu + (size_t)(b * 64 + o0    ) * HW + px);
    const ushort4 u1 = *(const ushort4*)(xtu + (size_t)(b * 64 + o0 + 1) * HW + px);
    const int kk[4] = {kv.x, kv.y, kv.z, kv.w};
    const float x0[4] = {bf2f(u0.x), bf2f(u0.y), bf2f(u0.z), bf2f(u0.w)};
    const float x1[4] = {bf2f(u1.x), bf2f(u1.y), bf2f(u1.z), bf2f(u1.w)};
    float4 o4a, o4b;
    float* oa = (float*)&o4a; float* ob = (float*)&o4b;
#pragma unroll
    for (int j = 0; j < 4; ++j) {
      const float2 am = *(const float2*)&am_s[kk[j] * 2];
      oa[j] = fmaf(fmaxf(x0[j] + am.x, 0.f), c0, h0);
      ob[j] = fmaf(fmaxf(x1[j] + am.y, 0.f), c1, h1);
    }
    *(float4*)(out + (size_t)(b * 64 + o0    ) * HW + px) = o4a;
    *(float4*)(out + (size_t)(b * 64 + o0 + 1) * HW + px) = o4b;
  }
}

extern "C" void kernel_launch(void* const* d_in, const int* in_sizes, int n_in,
                              void* d_out, int out_size, void* d_ws, size_t ws_size,
                              hipStream_t stream) {
  const float* x     = (const float*)d_in[0];
  const int*   index = (const int*)d_in[1];
  const float* Wft   = (const float*)d_in[2];
  const float* Wm    = (const float*)d_in[3];
  const float* gamma = (const float*)d_in[4];
  const float* beta  = (const float*)d_in[5];
  float* ws  = (float*)d_ws;
  float* out = (float*)d_out;
  unsigned* cnt = (unsigned*)d_out;   // counters live in out[0..1]; K4 overwrites

  k1_xt_bins_inv<<<513, 256, 0, stream>>>(x, index, Wft, Wm, ws, cnt);
  kmid<<<512, 256, 0, stream>>>(index, ws, cnt);
  k4_out<<<512, 256, 0, stream>>>(index, gamma, beta, ws, out);
}

// Round 3
// 153.111 us; speedup vs baseline: 2.2567x; 1.6583x over previous
//
#include <hip/hip_runtime.h>
#include <hip/hip_bf16.h>

// Problem constants
#define CIN   128
#define COUT  64
#define HW    16384   // 128*128

typedef __hip_bfloat16 bf16;

// Workspace layout (float offsets)
#define OFF_XT    0u          // bf16[2][64][16384]  xt
#define OFF_PS    1048576u    // bf16[512 blk][64 k][64 o] partial bin sums
#define OFF_PC    2097152u    // f32 [2][64][256]    partial bin counts
#define OFF_INV   2138240u    // f32 [64][64]        inv(cov)
#define OFF_ADJM  2142336u    // f32 [2][64][64]     adj @ means
#define OFF_BNP   2150528u    // f32 [32 oc][16 b*tile] float4 {s0,s1,ss0,ss1}

__device__ __forceinline__ unsigned short f2bfu(float f) {
  union { bf16 h; unsigned short u; } cv; cv.h = __float2bfloat16(f); return cv.u;
}
__device__ __forceinline__ float bf2f(unsigned short u) {
  union { unsigned int i; float f; } cv; cv.i = ((unsigned int)u) << 16; return cv.f;
}

#define FMA16() do { \
  acc[ 0]=fmaf(xv.x,wv.x,acc[ 0]); acc[ 1]=fmaf(xv.y,wv.x,acc[ 1]); \
  acc[ 2]=fmaf(xv.z,wv.x,acc[ 2]); acc[ 3]=fmaf(xv.w,wv.x,acc[ 3]); \
  acc[ 4]=fmaf(xv.x,wv.y,acc[ 4]); acc[ 5]=fmaf(xv.y,wv.y,acc[ 5]); \
  acc[ 6]=fmaf(xv.z,wv.y,acc[ 6]); acc[ 7]=fmaf(xv.w,wv.y,acc[ 7]); \
  acc[ 8]=fmaf(xv.x,wv.z,acc[ 8]); acc[ 9]=fmaf(xv.y,wv.z,acc[ 9]); \
  acc[10]=fmaf(xv.z,wv.z,acc[10]); acc[11]=fmaf(xv.w,wv.z,acc[11]); \
  acc[12]=fmaf(xv.x,wv.w,acc[12]); acc[13]=fmaf(xv.y,wv.w,acc[13]); \
  acc[14]=fmaf(xv.z,wv.w,acc[14]); acc[15]=fmaf(xv.w,wv.w,acc[15]); \
} while (0)

// ============================================================================
// K1: xt = einsum (bf16 out) + per-block bin partials; block 0 = inv(Wm Wm^T).
// Verbatim proven 121us baseline.
// ============================================================================
__global__ __launch_bounds__(256, 2) void k1_xt_bins_inv(
    const float* __restrict__ x, const int* __restrict__ index,
    const float* __restrict__ Wft, const float* __restrict__ Wm,
    float* __restrict__ ws)
{
  __shared__ __align__(16) float smem[16384];   // 64 KB
  const int blk = blockIdx.x, tid = threadIdx.x;
  if (blk != 0) {
    float* xl = smem;          // [128 c][64 px]
    float* wl = smem + 8192;   // [128 c][64 o]
    const int eb = blk - 1;
    const int b = eb >> 8, ps = eb & 255;
    const float* xg = x + (size_t)b * CIN * HW + ps * 64;
#pragma unroll
    for (int j = 0; j < 8; ++j) {
      const int fj = j * 256 + tid;
      const int c = fj >> 4, q4 = (fj & 15) * 4;
      *(float4*)&xl[c * 64 + q4] = *(const float4*)(xg + (size_t)c * HW + q4);
      *(float4*)&wl[c * 64 + q4] = *(const float4*)(Wft + c * 64 + q4);
    }
    __syncthreads();
    const int px_grp = tid & 15, o_grp = tid >> 4;
    const int px = ps * 64 + px_grp * 4, o0 = o_grp * 4;
    float acc[16];
#pragma unroll
    for (int j = 0; j < 16; ++j) acc[j] = 0.f;
#pragma unroll 8
    for (int c = 0; c < 128; ++c) {
      const float4 xv = *(const float4*)&xl[c * 64 + px_grp * 4];
      const float4 wv = *(const float4*)&wl[c * 64 + o0];
      FMA16();
    }
    unsigned short* xtu = (unsigned short*)(ws + OFF_XT);
#pragma unroll
    for (int oj = 0; oj < 4; ++oj) {
      ushort4 u;
      u.x = f2bfu(acc[oj*4+0]); u.y = f2bfu(acc[oj*4+1]);
      u.z = f2bfu(acc[oj*4+2]); u.w = f2bfu(acc[oj*4+3]);
      *(ushort4*)(xtu + (size_t)(b * 64 + o0 + oj) * HW + px) = u;
    }
    const int4 kv = *(const int4*)(index + b * HW + px);
    const int kk[4] = {kv.x, kv.y, kv.z, kv.w};
    __syncthreads();
    float* bins = smem;
    float* cnt_s = smem + 64 * 68;
    for (int i = tid; i < 64 * 68 + 64; i += 256) smem[i] = 0.f;
    __syncthreads();
#pragma unroll
    for (int pj = 0; pj < 4; ++pj) {
      const int kb = kk[pj] * 68 + o0;
      atomicAdd(&bins[kb    ], acc[ 0 + pj]);
      atomicAdd(&bins[kb + 1], acc[ 4 + pj]);
      atomicAdd(&bins[kb + 2], acc[ 8 + pj]);
      atomicAdd(&bins[kb + 3], acc[12 + pj]);
    }
    if (o_grp == 0) {
#pragma unroll
      for (int pj = 0; pj < 4; ++pj) atomicAdd(&cnt_s[kk[pj]], 1.f);
    }
    __syncthreads();
    unsigned short* pb = (unsigned short*)(ws + OFF_PS) + (size_t)eb * 4096;
    {
      const int k = tid >> 2, ob = (tid & 3) * 16;
#pragma unroll
      for (int q = 0; q < 4; ++q) {
        const float4 v = *(const float4*)&bins[k * 68 + ob + q * 4];
        ushort4 u;
        u.x = f2bfu(v.x); u.y = f2bfu(v.y); u.z = f2bfu(v.z); u.w = f2bfu(v.w);
        *(ushort4*)(pb + k * 64 + ob + q * 4) = u;
      }
    }
    if (tid < 64) ws[OFF_PC + (size_t)(b * 64 + tid) * 256 + ps] = cnt_s[tid];
  } else {
    // inverse block: blocked Gauss-Jordan, 16 panels of 4 pivots (proven form)
    float* wm = smem;
    float* Rb = smem + 8192;
    float* Cb = smem + 8704;
    for (int e = tid; e < 4096; e += 256) wm[(e >> 6) * 68 + (e & 63)] = Wm[e];
    __syncthreads();
    const int ig = tid >> 4, jg = tid & 15;
    const int i0 = ig << 2, j0 = jg << 2;
    float c4[16];
#pragma unroll
    for (int q = 0; q < 16; ++q) c4[q] = 0.f;
    for (int cq = 0; cq < 64; cq += 4) {
      float4 a[4], bb[4];
#pragma unroll
      for (int ii = 0; ii < 4; ++ii) a[ii]  = *(const float4*)&wm[(i0+ii)*68 + cq];
#pragma unroll
      for (int jj = 0; jj < 4; ++jj) bb[jj] = *(const float4*)&wm[(j0+jj)*68 + cq];
#pragma unroll
      for (int ii = 0; ii < 4; ++ii)
#pragma unroll
        for (int jj = 0; jj < 4; ++jj)
          c4[ii*4+jj] = fmaf(a[ii].x, bb[jj].x, fmaf(a[ii].y, bb[jj].y,
                        fmaf(a[ii].z, bb[jj].z, fmaf(a[ii].w, bb[jj].w, c4[ii*4+jj]))));
    }
    __syncthreads();
    __builtin_amdgcn_s_setprio(3);
    int buf = 0;
#pragma unroll 1   // MUST stay rolled (I$ thrash)
    for (int p = 0; p < 16; ++p) {
      const int P = p << 2;
      float* Rp = Rb + buf * 256;
      float* Cp = Cb + buf * 256;
      if (ig == p) {
#pragma unroll
        for (int r = 0; r < 4; ++r) {
          float4 t; t.x = c4[r*4+0]; t.y = c4[r*4+1]; t.z = c4[r*4+2]; t.w = c4[r*4+3];
          *(float4*)&Rp[r * 64 + j0] = t;
        }
      }
      if (jg == p) {
#pragma unroll
        for (int ii = 0; ii < 4; ++ii) {
          float4 t; t.x = c4[ii*4+0]; t.y = c4[ii*4+1]; t.z = c4[ii*4+2]; t.w = c4[ii*4+3];
          *(float4*)&Cp[(i0 + ii) * 4] = t;
        }
      }
      __syncthreads();
      float dd[16], cc[16], rr[16];
#pragma unroll
      for (int r = 0; r < 4; ++r) *(float4*)&dd[r * 4] = *(const float4*)&Rp[r * 64 + P];
#pragma unroll
      for (int ii = 0; ii < 4; ++ii) *(float4*)&cc[ii * 4] = *(const float4*)&Cp[(i0 + ii) * 4];
#pragma unroll
      for (int r = 0; r < 4; ++r) *(float4*)&rr[r * 4] = *(const float4*)&Rp[r * 64 + j0];
#pragma unroll
      for (int k = 0; k < 4; ++k) {
        const float rp = __builtin_amdgcn_rcpf(dd[k * 4 + k]);
        float ai[4], s[4];
#pragma unroll
        for (int j = 0; j < 4; ++j) s[j] = dd[k * 4 + j];
#pragma unroll
        for (int i = 0; i < 4; ++i) ai[i] = (i == k) ? (rp - 1.0f) : (-dd[i * 4 + k] * rp);
#pragma unroll
        for (int i = 0; i < 4; ++i)
#pragma unroll
          for (int j = 0; j < 4; ++j) dd[i * 4 + j] = fmaf(ai[i], s[j], dd[i * 4 + j]);
#pragma unroll
        for (int i = 0; i < 4; ++i) dd[i * 4 + k] = (i == k) ? rp : ai[i];
      }
      float T[16];
#pragma unroll
      for (int ii = 0; ii < 4; ++ii)
#pragma unroll
        for (int c = 0; c < 4; ++c) {
          float t = cc[ii*4+0] * dd[0*4+c];
          t = fmaf(cc[ii*4+1], dd[1*4+c], t);
          t = fmaf(cc[ii*4+2], dd[2*4+c], t);
          t = fmaf(cc[ii*4+3], dd[3*4+c], t);
          T[ii*4+c] = t;
        }
      if (ig == p && jg == p) {
#pragma unroll
        for (int q = 0; q < 16; ++q) c4[q] = dd[q];
      } else if (ig == p) {
#pragma unroll
        for (int r = 0; r < 4; ++r)
#pragma unroll
          for (int jj = 0; jj < 4; ++jj) {
            float t = dd[r*4+0] * rr[0*4+jj];
            t = fmaf(dd[r*4+1], rr[1*4+jj], t);
            t = fmaf(dd[r*4+2], rr[2*4+jj], t);
            t = fmaf(dd[r*4+3], rr[3*4+jj], t);
            c4[r*4+jj] = t;
          }
      } else if (jg == p) {
#pragma unroll
        for (int q = 0; q < 16; ++q) c4[q] = -T[q];
      } else {
#pragma unroll
        for (int ii = 0; ii < 4; ++ii)
#pragma unroll
          for (int jj = 0; jj < 4; ++jj) {
            float t = c4[ii*4+jj];
            t = fmaf(-T[ii*4+0], rr[0*4+jj], t);
            t = fmaf(-T[ii*4+1], rr[1*4+jj], t);
            t = fmaf(-T[ii*4+2], rr[2*4+jj], t);
            t = fmaf(-T[ii*4+3], rr[3*4+jj], t);
            c4[ii*4+jj] = t;
          }
      }
      buf ^= 1;
    }
    __builtin_amdgcn_s_setprio(0);
#pragma unroll
    for (int ii = 0; ii < 4; ++ii)
#pragma unroll
      for (int jj = 0; jj < 4; ++jj)
        ws[OFF_INV + (size_t)(i0 + ii) * 64 + j0 + jj] = c4[ii*4+jj];
  }
}

// ============================================================================
// K2': 16 blocks x 1024 thr. Each block (bb = blk>>3, r0 = (blk&7)*8):
//   1. counts for its b from PC (redundant x8, trivial)
//   2. full means[64][64] for its b from PS partials (redundant x8, L3-absorbed)
//   3. T = means@inv, d = diag, adj rows r0..r0+7, adjm -> ws
// Eliminates the K15 launch (~25us boundary) and the OFF_MEANS round-trip.
// ============================================================================
__global__ __launch_bounds__(1024) void k2_means_adj(float* __restrict__ ws)
{
  __shared__ __align__(16) float smem[9920];   // 39.7 KB
  float* means_s = smem;            // [64][68]
  float* inv_s   = smem + 4352;     // [64][68]
  float* T_s     = smem + 8704;     // [8][68]
  float* adj_s   = smem + 9248;     // [8][68]
  float* d_s     = smem + 9792;     // [64]
  float* cnt_s   = smem + 9856;     // [64]
  const int blk = blockIdx.x, tid = threadIdx.x;
  const int bb = blk >> 3, r0 = (blk & 7) << 3;

  // ---- 1. counts: thread (k = tid>>4, i = tid&15) sums PC[bb][k][i*16..i*16+15]
  {
    const int k = tid >> 4, i = tid & 15;
    const float* pc = ws + OFF_PC + (size_t)(bb * 64 + k) * 256 + i * 16;
    float c = 0.f;
#pragma unroll
    for (int q = 0; q < 4; ++q) {
      const float4 v = *(const float4*)(pc + q * 4);
      c += (v.x + v.y) + (v.z + v.w);
    }
    // reduce over the 16 lanes sharing k (consecutive lanes)
#pragma unroll
    for (int m = 1; m < 16; m <<= 1) c += __shfl_xor(c, m, 64);
    if (i == 0) cnt_s[k] = c;
  }
  __syncthreads();
  // ---- 2. means: thread (k = tid>>4, o4 = (tid&15)*4) sums 256 slabs of PS[slab][k][o4..o4+3]
  {
    const int k = tid >> 4, o4 = (tid & 15) * 4;
    const unsigned short* psu = (const unsigned short*)(ws + OFF_PS) + (size_t)bb * 256 * 4096 + k * 64 + o4;
    float s0 = 0.f, s1 = 0.f, s2 = 0.f, s3 = 0.f;
#pragma unroll 8
    for (int slab = 0; slab < 256; ++slab) {
      const ushort4 u = *(const ushort4*)(psu + (size_t)slab * 4096);
      s0 += bf2f(u.x); s1 += bf2f(u.y); s2 += bf2f(u.z); s3 += bf2f(u.w);
    }
    const float cntv = cnt_s[k];
    const float rden = 1.f / (cntv + ((cntv == 0.f) ? 1.f : 0.f));
    float4 m4; m4.x = s0 * rden; m4.y = s1 * rden; m4.z = s2 * rden; m4.w = s3 * rden;
    *(float4*)&means_s[k * 68 + o4] = m4;
  }
  // ---- load inv (symmetric) into LDS
  for (int e = tid; e < 4096; e += 1024) inv_s[(e >> 6) * 68 + (e & 63)] = ws[OFF_INV + e];
  __syncthreads();
  // ---- 3a. T rows + diag (tid<256: thread = (row j = tid>>2, 16-col strip))
  if (tid < 256) {
    const int j = tid >> 2, oq = (tid & 3) << 4;
    float4 Ta[4];
#pragma unroll
    for (int v = 0; v < 4; ++v) { Ta[v].x = 0.f; Ta[v].y = 0.f; Ta[v].z = 0.f; Ta[v].w = 0.f; }
    for (int c = 0; c < 64; ++c) {
      const float mv = means_s[j * 68 + c];
#pragma unroll
      for (int v = 0; v < 4; ++v) {
        const float4 iv = *(const float4*)&inv_s[c * 68 + oq + v * 4];
        Ta[v].x = fmaf(mv, iv.x, Ta[v].x); Ta[v].y = fmaf(mv, iv.y, Ta[v].y);
        Ta[v].z = fmaf(mv, iv.z, Ta[v].z); Ta[v].w = fmaf(mv, iv.w, Ta[v].w);
      }
    }
    float dp = 0.f;
#pragma unroll
    for (int v = 0; v < 4; ++v) {
      const float4 mvv = *(const float4*)&means_s[j * 68 + oq + v * 4];
      dp = fmaf(Ta[v].x, mvv.x, dp); dp = fmaf(Ta[v].y, mvv.y, dp);
      dp = fmaf(Ta[v].z, mvv.z, dp); dp = fmaf(Ta[v].w, mvv.w, dp);
    }
    dp += __shfl_xor(dp, 1, 64);
    dp += __shfl_xor(dp, 2, 64);
    if ((tid & 3) == 0) d_s[j] = dp;
    if (j >= r0 && j < r0 + 8) {
#pragma unroll
      for (int v = 0; v < 4; ++v) *(float4*)&T_s[(j - r0) * 68 + oq + v * 4] = Ta[v];
    }
  }
  __syncthreads();
  // ---- 3b. adj rows: q_ij = d_i + d_j - 2 T_i.m_j ; adj = exp(-sqrt(max(q,1e-12)))
  if (tid < 256) {
    const int i = tid >> 5, jb = tid & 31;
#pragma unroll
    for (int jj = 0; jj < 2; ++jj) {
      const int jc = jb + (jj << 5);
      float4 p4 = {0.f, 0.f, 0.f, 0.f};
      for (int dq = 0; dq < 64; dq += 4) {
        const float4 tv = *(const float4*)&T_s[i * 68 + dq];
        const float4 mv = *(const float4*)&means_s[jc * 68 + dq];
        p4.x = fmaf(tv.x, mv.x, p4.x); p4.y = fmaf(tv.y, mv.y, p4.y);
        p4.z = fmaf(tv.z, mv.z, p4.z); p4.w = fmaf(tv.w, mv.w, p4.w);
      }
      const float p = (p4.x + p4.y) + (p4.z + p4.w);
      const float q = d_s[r0 + i] + d_s[jc] - 2.f * p;
      adj_s[i * 68 + jc] = __expf(-sqrtf(fmaxf(q, 1e-12f)));
    }
  }
  __syncthreads();
  // ---- 3c. adjm rows -> ws
  if (tid < 128) {
    const int i = tid >> 4, oq4 = (tid & 15) << 2;
    float4 am = {0.f, 0.f, 0.f, 0.f};
    for (int jc = 0; jc < 64; ++jc) {
      const float av = adj_s[i * 68 + jc];
      const float4 mv = *(const float4*)&means_s[jc * 68 + oq4];
      am.x = fmaf(av, mv.x, am.x); am.y = fmaf(av, mv.y, am.y);
      am.z = fmaf(av, mv.z, am.z); am.w = fmaf(av, mv.w, am.w);
    }
    *(float4*)(ws + OFF_ADJM + (size_t)(bb * 64 + r0 + i) * 64 + oq4) = am;
  }
}

// ============================================================================
// K3: BN partial stats of f = relu(xt + adj_means[idx]). Verbatim baseline.
// ============================================================================
__global__ __launch_bounds__(256) void k3_bnstats(const int* __restrict__ index,
                                                  float* __restrict__ ws)
{
  __shared__ float am_s[128];
  __shared__ float red[4];
  const int blk = blockIdx.x, t = threadIdx.x;
  const int b = blk >> 8, oc = (blk >> 3) & 31, tile = blk & 7;
  const int o0 = oc * 2;
  if (t < 128) am_s[t] = ws[OFF_ADJM + (size_t)(b * 64 + (t >> 1)) * 64 + o0 + (t & 1)];
  if (t < 4) red[t] = 0.f;
  __syncthreads();
  const int lane = t & 63, w = t >> 6;
  const unsigned short* xtu = (const unsigned short*)(ws + OFF_XT);
  float s0 = 0.f, s1 = 0.f, q0 = 0.f, q1 = 0.f;
#pragma unroll
  for (int q = 0; q < 2; ++q) {
    const int px = tile * 2048 + (w * 2 + q) * 256 + lane * 4;
    const int4 kv = *(const int4*)(index + b * HW + px);
    const ushort4 u0 = *(const ushort4*)(xtu + (size_t)(b * 64 + o0    ) * HW + px);
    const ushort4 u1 = *(const ushort4*)(xtu + (size_t)(b * 64 + o0 + 1) * HW + px);
    const int kk[4] = {kv.x, kv.y, kv.z, kv.w};
    const float x0[4] = {bf2f(u0.x), bf2f(u0.y), bf2f(u0.z), bf2f(u0.w)};
    const float x1[4] = {bf2f(u1.x), bf2f(u1.y), bf2f(u1.z), bf2f(u1.w)};
#pragma unroll
    for (int j = 0; j < 4; ++j) {
      const float2 am = *(const float2*)&am_s[kk[j] * 2];
      const float f0 = fmaxf(x0[j] + am.x, 0.f);
      const float f1 = fmaxf(x1[j] + am.y, 0.f);
      s0 += f0; q0 = fmaf(f0, f0, q0);
      s1 += f1; q1 = fmaf(f1, f1, q1);
    }
  }
#pragma unroll
  for (int m = 1; m < 64; m <<= 1) {
    s0 += __shfl_xor(s0, m, 64); s1 += __shfl_xor(s1, m, 64);
    q0 += __shfl_xor(q0, m, 64); q1 += __shfl_xor(q1, m, 64);
  }
  if (lane == 0) {
    atomicAdd(&red[0], s0); atomicAdd(&red[1], s1);
    atomicAdd(&red[2], q0); atomicAdd(&red[3], q1);
  }
  __syncthreads();
  if (t == 0) {
    float4 v; v.x = red[0]; v.y = red[1]; v.z = red[2]; v.w = red[3];
    *(float4*)(ws + OFF_BNP + (size_t)(oc * 16 + b * 8 + tile) * 4) = v;
  }
}

// ============================================================================
// K4: redundant BN-final reduce per block, then out = f*scale + shift. Verbatim.
// ============================================================================
__global__ __launch_bounds__(256) void k4_out(const int* __restrict__ index,
    const float* __restrict__ gamma, const float* __restrict__ beta,
    const float* __restrict__ ws, float* __restrict__ out)
{
  __shared__ float am_s[128];
  __shared__ float4 tmp[16];
  __shared__ float sc_s[2], sh_s[2];
  const int blk = blockIdx.x, t = threadIdx.x;
  const int b = blk >> 8, oc = (blk >> 3) & 31, tile = blk & 7;
  const int o0 = oc * 2;
  if (t < 128) am_s[t] = ws[OFF_ADJM + (size_t)(b * 64 + (t >> 1)) * 64 + o0 + (t & 1)];
  if (t < 16) tmp[t] = *(const float4*)(ws + OFF_BNP + (size_t)(oc * 16 + t) * 4);
  if (t < 2) {   // same wave as tmp writers: per-wave LDS ordering suffices
    float s = 0.f, qq = 0.f;
#pragma unroll
    for (int i = 0; i < 16; ++i) {
      const float4 v = tmp[i];
      s  += (t == 0) ? v.x : v.y;
      qq += (t == 0) ? v.z : v.w;
    }
    const float mean = s * (1.f / 32768.f);
    const float var  = qq * (1.f / 32768.f) - mean * mean;
    const float sc = gamma[o0 + t] * rsqrtf(var + 1e-5f);
    sc_s[t] = sc;
    sh_s[t] = fmaf(-mean, sc, beta[o0 + t]);
  }
  __syncthreads();
  const int lane = t & 63, w = t >> 6;
  const unsigned short* xtu = (const unsigned short*)(ws + OFF_XT);
  const float c0 = sc_s[0], c1 = sc_s[1], h0 = sh_s[0], h1 = sh_s[1];
#pragma unroll
  for (int q = 0; q < 2; ++q) {
    const int px = tile * 2048 + (w * 2 + q) * 256 + lane * 4;
    const int4 kv = *(const int4*)(index + b * HW + px);
    const ushort4 u0 = *(const ushort4*)(xtu + (size_t)(b * 64 + o0    ) * HW + px);
    const ushort4 u1 = *(const ushort4*)(xtu + (size_t)(b * 64 + o0 + 1) * HW + px);
    const int kk[4] = {kv.x, kv.y, kv.z, kv.w};
    const float x0[4] = {bf2f(u0.x), bf2f(u0.y), bf2f(u0.z), bf2f(u0.w)};
    const float x1[4] = {bf2f(u1.x), bf2f(u1.y), bf2f(u1.z), bf2f(u1.w)};
    float4 o4a, o4b;
    float* oa = (float*)&o4a; float* ob = (float*)&o4b;
#pragma unroll
    for (int j = 0; j < 4; ++j) {
      const float2 am = *(const float2*)&am_s[kk[j] * 2];
      oa[j] = fmaf(fmaxf(x0[j] + am.x, 0.f), c0, h0);
      ob[j] = fmaf(fmaxf(x1[j] + am.y, 0.f), c1, h1);
    }
    *(float4*)(out + (size_t)(b * 64 + o0    ) * HW + px) = o4a;
    *(float4*)(out + (size_t)(b * 64 + o0 + 1) * HW + px) = o4b;
  }
}

extern "C" void kernel_launch(void* const* d_in, const int* in_sizes, int n_in,
                              void* d_out, int out_size, void* d_ws, size_t ws_size,
                              hipStream_t stream) {
  const float* x     = (const float*)d_in[0];
  const int*   index = (const int*)d_in[1];
  const float* Wft   = (const float*)d_in[2];
  const float* Wm    = (const float*)d_in[3];
  const float* gamma = (const float*)d_in[4];
  const float* beta  = (const float*)d_in[5];
  float* ws  = (float*)d_ws;
  float* out = (float*)d_out;

  k1_xt_bins_inv<<<513, 256, 0, stream>>>(x, index, Wft, Wm, ws);
  k2_means_adj<<<16, 1024, 0, stream>>>(ws);
  k3_bnstats<<<512, 256, 0, stream>>>(index, ws);
  k4_out<<<512, 256, 0, stream>>>(index, gamma, beta, ws, out);
}